// Round 2
// baseline (710.290 us; speedup 1.0000x reference)
//
#include <hip/hip_runtime.h>

// GATTP: encoder GEMM (dual-bf16 MFMA) -> gate GEMM (fp32) -> per-segment
// softmax-weighted pooling (1 block per segment, batch sorted) -> ReLU.
// N=100000, Din=1024, D=64, H=32, B=512. Output fp32 [512, 2048].
// NOTE: harness delivers integer inputs as int32 (batch is const int*).

typedef short bf16x8 __attribute__((ext_vector_type(8)));
typedef float f32x4 __attribute__((ext_vector_type(4)));

#define NUM_GRAPHS 512
#define DIN 1024
#define DENC 64
#define NH 32
#define LDA 72   // bf16 pitch for A tiles (144 B rows, 16B-aligned)
#define LDB 72   // bf16 pitch for B tiles

__device__ __forceinline__ unsigned short f2bf(float f) {
    unsigned int u = __float_as_uint(f);
    return (unsigned short)((u + 0x7fffu + ((u >> 16) & 1u)) >> 16);
}
// split fp32 into hi/lo bf16 (RNE): hi + lo represents f to ~2^-18 rel.
__device__ __forceinline__ void split2(float f, unsigned short& h, unsigned short& l) {
    unsigned int u = __float_as_uint(f);
    unsigned int hb = (u + 0x7fffu + ((u >> 16) & 1u)) >> 16;
    h = (unsigned short)hb;
    float hf = __uint_as_float(hb << 16);
    l = f2bf(f - hf);
}

__device__ __forceinline__ int clampseg(int v) {
    return v < 0 ? 0 : (v >= NUM_GRAPHS ? NUM_GRAPHS - 1 : v);
}

// ---------------- segment offsets from sorted batch (int32) ----------------
__global__ void k_seg(const int* __restrict__ batch, int* __restrict__ seg, int N) {
    int n = blockIdx.x * 256 + threadIdx.x;
    if (n >= N) return;
    int bc = clampseg(batch[n]);
    if (n == 0) {
        for (int j = 0; j <= bc; ++j) seg[j] = 0;
        int bl = clampseg(batch[N - 1]);
        for (int j = bl + 1; j <= NUM_GRAPHS; ++j) seg[j] = N;
    } else {
        int bp = clampseg(batch[n - 1]);
        for (int j = bp + 1; j <= bc; ++j) seg[j] = n;
    }
}

// ---------------- W_enc fp32 -> hi/lo bf16 ----------------
__global__ void k_convw(const float* __restrict__ W,
                        unsigned short* __restrict__ Wh,
                        unsigned short* __restrict__ Wl) {
    int idx = (blockIdx.x * 256 + threadIdx.x) * 4;  // exactly 65536 elems
    float4 v = *(const float4*)(W + idx);
    ushort4 h4, l4;
    split2(v.x, h4.x, l4.x);
    split2(v.y, h4.y, l4.y);
    split2(v.z, h4.z, l4.z);
    split2(v.w, h4.w, l4.w);
    *(ushort4*)(Wh + idx) = h4;
    *(ushort4*)(Wl + idx) = l4;
}

// ---------------- xe = x @ W_enc^T + b_enc  (dual-bf16 MFMA) ----------------
// 128 rows/block, BK=64, 4 waves; wave w owns rows [32w,32w+32) x all 64 cols.
__global__ __launch_bounds__(256, 2) void k_gemm(
    const float* __restrict__ x,            // [N, 1024]
    const unsigned short* __restrict__ Wh,  // [64, 1024] bf16 hi
    const unsigned short* __restrict__ Wl,  // [64, 1024] bf16 lo
    const float* __restrict__ b_enc,        // [64]
    float* __restrict__ xe,                 // [N, 64]
    int N)
{
    __shared__ unsigned short Ah[128 * LDA], Al[128 * LDA];
    __shared__ unsigned short Bh[64 * LDB],  Bl[64 * LDB];

    const int tid  = threadIdx.x;
    const int lane = tid & 63;
    const int wv   = tid >> 6;
    const long brow = (long)blockIdx.x * 128;

    f32x4 acc[2][4];
    #pragma unroll
    for (int i = 0; i < 2; ++i)
        #pragma unroll
        for (int j = 0; j < 4; ++j) acc[i][j] = (f32x4){0.f, 0.f, 0.f, 0.f};

    const int ar0 = tid >> 4;           // A staging: rows ar0 + 16*i
    const int ac4 = (tid & 15) * 4;     // 4-float column chunk
    const int br0 = tid >> 3;           // B staging: rows br0 + 32*i
    const int bc8 = (tid & 7) * 8;      // 8-bf16 column chunk
    const int fr  = lane & 15;          // fragment row/col within 16-tile
    const int fq  = lane >> 4;          // quad -> k sub-offset

    for (int k0 = 0; k0 < DIN; k0 += 64) {
        // ---- stage A (fp32 -> hi/lo bf16), zero-fill OOB rows ----
        #pragma unroll
        for (int i = 0; i < 8; ++i) {
            int row = ar0 + 16 * i;
            long gr = brow + row;
            float4 v = {0.f, 0.f, 0.f, 0.f};
            if (gr < N) v = *(const float4*)(x + gr * DIN + k0 + ac4);
            ushort4 h4, l4;
            split2(v.x, h4.x, l4.x);
            split2(v.y, h4.y, l4.y);
            split2(v.z, h4.z, l4.z);
            split2(v.w, h4.w, l4.w);
            *(ushort4*)&Ah[row * LDA + ac4] = h4;
            *(ushort4*)&Al[row * LDA + ac4] = l4;
        }
        // ---- stage B (already bf16) ----
        #pragma unroll
        for (int i = 0; i < 2; ++i) {
            int row = br0 + 32 * i;
            *(uint4*)&Bh[row * LDB + bc8] = *(const uint4*)(Wh + row * DIN + k0 + bc8);
            *(uint4*)&Bl[row * LDB + bc8] = *(const uint4*)(Wl + row * DIN + k0 + bc8);
        }
        __syncthreads();

        #pragma unroll
        for (int kk = 0; kk < 64; kk += 32) {
            bf16x8 ah[2], al[2];
            #pragma unroll
            for (int rt = 0; rt < 2; ++rt) {
                int o = (wv * 32 + rt * 16 + fr) * LDA + fq * 8 + kk;
                ah[rt] = *(const bf16x8*)&Ah[o];
                al[rt] = *(const bf16x8*)&Al[o];
            }
            #pragma unroll
            for (int ct = 0; ct < 4; ++ct) {
                int o = (ct * 16 + fr) * LDB + fq * 8 + kk;
                bf16x8 bh = *(const bf16x8*)&Bh[o];
                bf16x8 bl = *(const bf16x8*)&Bl[o];
                #pragma unroll
                for (int rt = 0; rt < 2; ++rt) {
                    acc[rt][ct] = __builtin_amdgcn_mfma_f32_16x16x32_bf16(ah[rt], bh, acc[rt][ct], 0, 0, 0);
                    acc[rt][ct] = __builtin_amdgcn_mfma_f32_16x16x32_bf16(ah[rt], bl, acc[rt][ct], 0, 0, 0);
                    acc[rt][ct] = __builtin_amdgcn_mfma_f32_16x16x32_bf16(al[rt], bh, acc[rt][ct], 0, 0, 0);
                }
            }
        }
        __syncthreads();
    }

    // ---- epilogue: C layout col=lane&15, row=(lane>>4)*4+reg ----
    float bv[4];
    #pragma unroll
    for (int ct = 0; ct < 4; ++ct) bv[ct] = b_enc[ct * 16 + fr];
    #pragma unroll
    for (int rt = 0; rt < 2; ++rt) {
        #pragma unroll
        for (int r = 0; r < 4; ++r) {
            long row = brow + wv * 32 + rt * 16 + fq * 4 + r;
            if (row < N) {
                float* o = xe + row * DENC;
                #pragma unroll
                for (int ct = 0; ct < 4; ++ct)
                    o[ct * 16 + fr] = acc[rt][ct][r] + bv[ct];
            }
        }
    }
}

// ---------------- gate = xe @ W_gate^T + b_gate (fp32, register-blocked) ----
__global__ __launch_bounds__(256) void k_gate(
    const float* __restrict__ xe,    // [N, 64]
    const float* __restrict__ Wg,    // [32, 64]
    const float* __restrict__ bg,    // [32]
    float* __restrict__ gate,        // [N, 32]
    int N)
{
    __shared__ float xs[128 * 68];
    __shared__ float wgs[32 * 68];
    __shared__ float bgs[32];
    const int tid = threadIdx.x;
    const long brow = (long)blockIdx.x * 128;

    for (int i = tid; i < NH * DENC; i += 256) wgs[(i >> 6) * 68 + (i & 63)] = Wg[i];
    if (tid < NH) bgs[tid] = bg[tid];

    const int r0s = tid >> 4, c4 = (tid & 15) * 4;
    #pragma unroll
    for (int i = 0; i < 8; ++i) {
        int row = r0s + 16 * i;
        long gr = brow + row;
        if (gr < N)
            *(float4*)&xs[row * 68 + c4] = *(const float4*)(xe + gr * DENC + c4);
    }
    __syncthreads();

    const int r0 = tid & 31;             // rows r0 + 32*i
    const int h0 = (tid >> 5) * 4;       // 4 heads per thread
    float acc[4][4] = {};
    #pragma unroll
    for (int k = 0; k < 64; k += 4) {
        float4 w0 = *(const float4*)&wgs[(h0 + 0) * 68 + k];
        float4 w1 = *(const float4*)&wgs[(h0 + 1) * 68 + k];
        float4 w2 = *(const float4*)&wgs[(h0 + 2) * 68 + k];
        float4 w3 = *(const float4*)&wgs[(h0 + 3) * 68 + k];
        #pragma unroll
        for (int i = 0; i < 4; ++i) {
            float4 xv = *(const float4*)&xs[(r0 + 32 * i) * 68 + k];
            acc[i][0] += xv.x * w0.x + xv.y * w0.y + xv.z * w0.z + xv.w * w0.w;
            acc[i][1] += xv.x * w1.x + xv.y * w1.y + xv.z * w1.z + xv.w * w1.w;
            acc[i][2] += xv.x * w2.x + xv.y * w2.y + xv.z * w2.z + xv.w * w2.w;
            acc[i][3] += xv.x * w3.x + xv.y * w3.y + xv.z * w3.z + xv.w * w3.w;
        }
    }
    #pragma unroll
    for (int i = 0; i < 4; ++i) {
        long row = brow + r0 + 32 * i;
        if (row < N) {
            float4 o = { acc[i][0] + bgs[h0 + 0], acc[i][1] + bgs[h0 + 1],
                         acc[i][2] + bgs[h0 + 2], acc[i][3] + bgs[h0 + 3] };
            *(float4*)(gate + row * NH + h0) = o;
        }
    }
}

// ---------------- per-segment softmax pooling + ReLU ----------------
// One block per segment. Wave w owns heads [8w, 8w+8); lane rl owns d=rl.
__global__ __launch_bounds__(256) void k_pool(
    const float* __restrict__ xe,    // [N, 64]
    const float* __restrict__ gate,  // [N, 32]
    const int* __restrict__ seg,     // [513]
    float* __restrict__ out,         // [512, 2048]
    int N)
{
    __shared__ float xs[64 * 68];
    __shared__ float gs[64 * 36];
    __shared__ float gmaxs[NH];
    __shared__ float gsums[NH];
    const int tid = threadIdx.x;
    const int b = blockIdx.x;
    const int s = seg[b], e = seg[b + 1];
    const long ob = (long)b * (NH * DENC);
    if (e <= s) {
        for (int i = tid; i < NH * DENC; i += 256) out[ob + i] = 0.f;
        return;
    }
    const int rl = tid & 63;
    const int hq = tid >> 6;
    const int h0 = hq * 8;

    // pass 1: per-head segment max (chunks of 64 rows, float4 gate loads)
    float vmax[8];
    #pragma unroll
    for (int j = 0; j < 8; ++j) vmax[j] = -INFINITY;
    for (int base = s; base < e; base += 64) {
        if (base + rl < e) {
            const float* g0 = gate + (long)(base + rl) * NH + h0;
            float4 a = *(const float4*)g0;
            float4 c = *(const float4*)(g0 + 4);
            vmax[0] = fmaxf(vmax[0], a.x); vmax[1] = fmaxf(vmax[1], a.y);
            vmax[2] = fmaxf(vmax[2], a.z); vmax[3] = fmaxf(vmax[3], a.w);
            vmax[4] = fmaxf(vmax[4], c.x); vmax[5] = fmaxf(vmax[5], c.y);
            vmax[6] = fmaxf(vmax[6], c.z); vmax[7] = fmaxf(vmax[7], c.w);
        }
    }
    #pragma unroll
    for (int off = 32; off > 0; off >>= 1)
        #pragma unroll
        for (int j = 0; j < 8; ++j) vmax[j] = fmaxf(vmax[j], __shfl_down(vmax[j], off));
    if (rl == 0)
        #pragma unroll
        for (int j = 0; j < 8; ++j) gmaxs[h0 + j] = vmax[j];
    __syncthreads();
    float gm[8];
    #pragma unroll
    for (int j = 0; j < 8; ++j) gm[j] = gmaxs[h0 + j];

    // pass 2: g = exp(gate-gmax); gsum; pooled[h][d] += g*xe
    float pool[8] = {0, 0, 0, 0, 0, 0, 0, 0};
    float gp[8] = {0, 0, 0, 0, 0, 0, 0, 0};
    const int r0s = tid >> 4, c4 = (tid & 15) * 4;
    for (int base = s; base < e; base += 64) {
        const int nrow = min(64, e - base);
        #pragma unroll
        for (int i = 0; i < 4; ++i) {
            int row = r0s + 16 * i;
            if (row < nrow)
                *(float4*)&xs[row * 68 + c4] = *(const float4*)(xe + (long)(base + row) * DENC + c4);
        }
        float4 ga = {0, 0, 0, 0}, gb = {0, 0, 0, 0};
        if (rl < nrow) {
            const float* g0 = gate + (long)(base + rl) * NH + h0;
            float4 a = *(const float4*)g0;
            float4 c = *(const float4*)(g0 + 4);
            ga.x = __expf(a.x - gm[0]); ga.y = __expf(a.y - gm[1]);
            ga.z = __expf(a.z - gm[2]); ga.w = __expf(a.w - gm[3]);
            gb.x = __expf(c.x - gm[4]); gb.y = __expf(c.y - gm[5]);
            gb.z = __expf(c.z - gm[6]); gb.w = __expf(c.w - gm[7]);
            gp[0] += ga.x; gp[1] += ga.y; gp[2] += ga.z; gp[3] += ga.w;
            gp[4] += gb.x; gp[5] += gb.y; gp[6] += gb.z; gp[7] += gb.w;
        }
        *(float4*)&gs[rl * 36 + h0] = ga;
        *(float4*)&gs[rl * 36 + h0 + 4] = gb;
        __syncthreads();
        #pragma unroll 4
        for (int r2 = 0; r2 < nrow; ++r2) {
            float xv = xs[r2 * 68 + rl];
            float4 g1 = *(const float4*)&gs[r2 * 36 + h0];
            float4 g2 = *(const float4*)&gs[r2 * 36 + h0 + 4];
            pool[0] += g1.x * xv; pool[1] += g1.y * xv;
            pool[2] += g1.z * xv; pool[3] += g1.w * xv;
            pool[4] += g2.x * xv; pool[5] += g2.y * xv;
            pool[6] += g2.z * xv; pool[7] += g2.w * xv;
        }
        __syncthreads();
    }
    #pragma unroll
    for (int off = 32; off > 0; off >>= 1)
        #pragma unroll
        for (int j = 0; j < 8; ++j) gp[j] += __shfl_down(gp[j], off);
    if (rl == 0)
        #pragma unroll
        for (int j = 0; j < 8; ++j) gsums[h0 + j] = gp[j];
    __syncthreads();
    #pragma unroll
    for (int j = 0; j < 8; ++j) {
        float v = pool[j] / gsums[h0 + j];
        out[ob + (h0 + j) * DENC + rl] = fmaxf(v, 0.f);
    }
}

extern "C" void kernel_launch(void* const* d_in, const int* in_sizes, int n_in,
                              void* d_out, int out_size, void* d_ws, size_t ws_size,
                              hipStream_t stream)
{
    const float* x      = (const float*)d_in[0];
    const int* batch    = (const int*)d_in[1];   // int64 in reference -> int32 from harness
    const float* W_enc  = (const float*)d_in[2];
    const float* b_enc  = (const float*)d_in[3];
    const float* W_gate = (const float*)d_in[4];
    const float* b_gate = (const float*)d_in[5];
    float* out = (float*)d_out;
    const int N = in_sizes[1];

    char* ws = (char*)d_ws;
    size_t off = 0;
    auto take = [&](size_t bytes) {
        char* p = ws + off;
        off += (bytes + 255) & ~(size_t)255;
        return p;
    };
    float* xe  = (float*)take((size_t)N * DENC * sizeof(float));   // 25.6 MB
    float* gate = (float*)take((size_t)N * NH * sizeof(float));    // 12.8 MB
    unsigned short* Wh = (unsigned short*)take((size_t)DENC * DIN * 2);
    unsigned short* Wl = (unsigned short*)take((size_t)DENC * DIN * 2);
    int* seg = (int*)take((NUM_GRAPHS + 1) * sizeof(int));
    (void)ws_size; (void)n_in; (void)out_size;

    k_seg<<<(N + 255) / 256, 256, 0, stream>>>(batch, seg, N);
    k_convw<<<(DENC * DIN) / 1024, 256, 0, stream>>>(W_enc, Wh, Wl);
    k_gemm<<<(N + 127) / 128, 256, 0, stream>>>(x, Wh, Wl, b_enc, xe, N);
    k_gate<<<(N + 127) / 128, 256, 0, stream>>>(xe, W_gate, b_gate, gate, N);
    k_pool<<<NUM_GRAPHS, 256, 0, stream>>>(xe, gate, seg, out, N);
}